// Round 5
// baseline (396.004 us; speedup 1.0000x reference)
//
#include <hip/hip_runtime.h>

// Dims
#define WD 128   // W_STEPS
#define ED 16    // E
#define ND 512   // B*I
#define FD 64    // F
#define PD 72    // P = 8 + F

// Fast math: v_exp_f32 (exp2) + v_rcp_f32. ~1 ulp each.
#define LOG2E  1.44269504088896340736f
#define LOG2E2 2.88539008177792681472f
__device__ __forceinline__ float fast_sig(float x) {
    return __builtin_amdgcn_rcpf(1.0f + __builtin_amdgcn_exp2f(-LOG2E * x));
}
__device__ __forceinline__ float fast_tanh(float x) {
    // tanh = 1 - 2/(e^{2x}+1); saturates correctly at +/-inf
    return 1.0f - 2.0f * __builtin_amdgcn_rcpf(1.0f + __builtin_amdgcn_exp2f(LOG2E2 * x));
}

// ws layout (floats): [0..3071] Wc[48][64], [3072..3119] bc[48],
//                     [4096 ..] gx[E][W][3][N]  (3,145,728 floats = 12 MB)
#define GX_OFF 4096

// ---------------------------------------------------------------------------
// Prep: 48 blocks (one per (e,g) row), 64 threads (one per f).
// ---------------------------------------------------------------------------
__global__ __launch_bounds__(64) void gru_prep(
    const float* __restrict__ wl,   // (E,P,F)
    const float* __restrict__ bl,   // (E,P)
    const float* __restrict__ wih,  // (E,3,P)
    const float* __restrict__ bih,  // (E,3)
    float* __restrict__ ws)
{
    const int eg = blockIdx.x;          // 0..47
    const int e  = eg / 3;
    const int f  = threadIdx.x;         // 0..63

    const float* a = wih + eg * PD;
    const float* w = wl + (size_t)e * PD * FD + f;
    float s = 0.0f;
    #pragma unroll 8
    for (int p = 0; p < PD; ++p) s = fmaf(a[p], w[p * FD], s);
    ws[eg * FD + f] = s;

    const float* b = bl + (size_t)e * PD;
    float pv = a[f] * b[f];
    if (f < 8) pv = fmaf(a[64 + f], b[64 + f], pv);
    pv += __shfl_xor(pv, 1, 64);
    pv += __shfl_xor(pv, 2, 64);
    pv += __shfl_xor(pv, 4, 64);
    pv += __shfl_xor(pv, 8, 64);
    pv += __shfl_xor(pv, 16, 64);
    pv += __shfl_xor(pv, 32, 64);
    if (f == 0) ws[ED * 3 * FD + eg] = pv + bih[eg];
}

// ---------------------------------------------------------------------------
// Phase 1: projection. gx[e][w][g][n] = sum_f Wc[e][g][f] * x[w][e][n][f]
// 2048 blocks x 256 thr = 8192 waves (8/SIMD). Wave: 4 rows/iter, 32 iters.
// lane = r*16+c: group r = row-in-wave, c = f-chunk (float4).
// Per iter: one 1KB coalesced wave load, 12 FMA, 4 butterfly rounds,
// lanes c<3 write gate c. (e,n) fixed per wave across iters; w += 4.
// ---------------------------------------------------------------------------
__global__ __launch_bounds__(256) void gru_proj(
    const float* __restrict__ x,    // (W,E,N,F)
    const float* __restrict__ ws,   // Wc
    float* __restrict__ gx)         // (E,W,3,N)
{
    const int lane = threadIdx.x & 63;
    const int wid  = (blockIdx.x << 2) + (threadIdx.x >> 6); // 0..8191
    const int c    = lane & 15;
    const int r    = lane >> 4;

    const int R = (wid << 2) + r;        // row id, iter 0 (rows advance +32768)
    const int n = R & (ND - 1);
    const int e = (R >> 9) & (ED - 1);   // invariant across iters (64 % 16 == 0... e-step = 64 ≡ 0 mod 16)
    const int w0i = R >> 13;             // 0..3; w = w0i + 4*it

    const float* Wc = ws;
    const float4 wv0 = *(const float4*)(Wc + (e * 3 + 0) * FD + c * 4);
    const float4 wv1 = *(const float4*)(Wc + (e * 3 + 1) * FD + c * 4);
    const float4 wv2 = *(const float4*)(Wc + (e * 3 + 2) * FD + c * 4);

    const float* px = x + (size_t)R * FD + c * 4;
    float* pg = gx + ((size_t)(e * WD + w0i) * 3 + c) * ND + n;  // c>=3: never stored
    const size_t xadv = (size_t)32768 * FD;   // 32768 rows per iter
    const size_t gadv = (size_t)4 * 3 * ND;   // w += 4

    float4 X = *(const float4*)px; px += xadv;
    for (int it = 0; it < 32; ++it) {
        const float4 Xc = X;
        if (it < 31) { X = *(const float4*)px; px += xadv; }
        float s0 = Xc.x * wv0.x, s1 = Xc.x * wv1.x, s2 = Xc.x * wv2.x;
        s0 = fmaf(Xc.y, wv0.y, s0); s1 = fmaf(Xc.y, wv1.y, s1); s2 = fmaf(Xc.y, wv2.y, s2);
        s0 = fmaf(Xc.z, wv0.z, s0); s1 = fmaf(Xc.z, wv1.z, s1); s2 = fmaf(Xc.z, wv2.z, s2);
        s0 = fmaf(Xc.w, wv0.w, s0); s1 = fmaf(Xc.w, wv1.w, s1); s2 = fmaf(Xc.w, wv2.w, s2);
        s0 += __shfl_xor(s0, 1, 64); s1 += __shfl_xor(s1, 1, 64); s2 += __shfl_xor(s2, 1, 64);
        s0 += __shfl_xor(s0, 2, 64); s1 += __shfl_xor(s1, 2, 64); s2 += __shfl_xor(s2, 2, 64);
        s0 += __shfl_xor(s0, 4, 64); s1 += __shfl_xor(s1, 4, 64); s2 += __shfl_xor(s2, 4, 64);
        s0 += __shfl_xor(s0, 8, 64); s1 += __shfl_xor(s1, 8, 64); s2 += __shfl_xor(s2, 8, 64);
        float sv = s0;
        sv = (c == 1) ? s1 : sv;
        sv = (c == 2) ? s2 : sv;
        if (c < 3) *pg = sv;
        pg += gadv;
    }
}

// ---------------------------------------------------------------------------
// Phase 2: scan. One lane per chain, no cross-lane ops.
// 128 blocks x 64 thr. Wave: e = bid>>3, n = (bid&7)*64 + lane.
// gx reads (12 B/lane/step) are h-independent -> depth-8 register queue.
// ---------------------------------------------------------------------------
__global__ __launch_bounds__(64) void gru_scan(
    const float* __restrict__ gx,   // (E,W,3,N)
    const float* __restrict__ st,   // (E,N)
    const float* __restrict__ whh,  // (E,3)
    const float* __restrict__ bhh,  // (E,3)
    const float* __restrict__ ws,   // for bc
    float* __restrict__ out)        // (W,E,N)
{
    const int lane = threadIdx.x;
    const int bid  = blockIdx.x;        // 0..127
    const int e    = bid >> 3;
    const int n    = ((bid & 7) << 6) + lane;

    const float* bc = ws + ED * 3 * FD;
    const float wh0 = whh[e * 3 + 0], wh1 = whh[e * 3 + 1], wh2 = whh[e * 3 + 2];
    const float B0  = bc[e * 3 + 0] + bhh[e * 3 + 0];
    const float B1  = bc[e * 3 + 1] + bhh[e * 3 + 1];
    const float bc2 = bc[e * 3 + 2];
    const float bh2 = bhh[e * 3 + 2];

    float h = st[e * ND + n];
    const float* pg = gx + (size_t)e * WD * 3 * ND + n;
    float* po = out + (size_t)e * ND + n;

#define LOADQ(A, B, C, wq) { const float* p_ = pg + (size_t)(wq) * (3 * ND); \
                             A = p_[0]; B = p_[ND]; C = p_[2 * ND]; }
#define GSTEP(G0, G1, G2) { \
        const float rr = fast_sig((G0) + fmaf(h, wh0, B0));                   \
        const float zz = fast_sig((G1) + fmaf(h, wh1, B1));                   \
        const float nn = fast_tanh(fmaf(rr, fmaf(h, wh2, bh2), (G2) + bc2));  \
        h = fmaf(zz, h - nn, nn);                                             \
        *po = h; po += (size_t)ED * ND; }

    float a0,a1,a2, b0,b1,b2, c0,c1,c2, d0,d1,d2,
          e0,e1,e2, f0,f1,f2, g0,g1,g2, h0,h1,h2;
    LOADQ(a0,a1,a2, 0); LOADQ(b0,b1,b2, 1); LOADQ(c0,c1,c2, 2); LOADQ(d0,d1,d2, 3);
    LOADQ(e0,e1,e2, 4); LOADQ(f0,f1,f2, 5); LOADQ(g0,g1,g2, 6); LOADQ(h0,h1,h2, 7);

    for (int w8 = 0; w8 < WD; w8 += 8) {
        const bool pf = (w8 + 8) < WD;
        { const float t0=a0,t1=a1,t2=a2; if (pf) LOADQ(a0,a1,a2, w8+8);  GSTEP(t0,t1,t2); }
        { const float t0=b0,t1=b1,t2=b2; if (pf) LOADQ(b0,b1,b2, w8+9);  GSTEP(t0,t1,t2); }
        { const float t0=c0,t1=c1,t2=c2; if (pf) LOADQ(c0,c1,c2, w8+10); GSTEP(t0,t1,t2); }
        { const float t0=d0,t1=d1,t2=d2; if (pf) LOADQ(d0,d1,d2, w8+11); GSTEP(t0,t1,t2); }
        { const float t0=e0,t1=e1,t2=e2; if (pf) LOADQ(e0,e1,e2, w8+12); GSTEP(t0,t1,t2); }
        { const float t0=f0,t1=f1,t2=f2; if (pf) LOADQ(f0,f1,f2, w8+13); GSTEP(t0,t1,t2); }
        { const float t0=g0,t1=g1,t2=g2; if (pf) LOADQ(g0,g1,g2, w8+14); GSTEP(t0,t1,t2); }
        { const float t0=h0,t1=h1,t2=h2; if (pf) LOADQ(h0,h1,h2, w8+15); GSTEP(t0,t1,t2); }
    }
#undef LOADQ
#undef GSTEP
}

// ---------------------------------------------------------------------------
extern "C" void kernel_launch(void* const* d_in, const int* in_sizes, int n_in,
                              void* d_out, int out_size, void* d_ws, size_t ws_size,
                              hipStream_t stream)
{
    const float* x    = (const float*)d_in[0];  // inputs (W,E,B,I,F)
    const float* st   = (const float*)d_in[1];  // state  (1,E,N,1)
    const float* wl   = (const float*)d_in[2];  // weight_linear (E,P,F)
    const float* bl   = (const float*)d_in[3];  // bias_linear   (E,P)
    const float* wih  = (const float*)d_in[4];  // w_ih (E,3,P)
    const float* whh  = (const float*)d_in[5];  // w_hh (E,3)
    const float* bih  = (const float*)d_in[6];  // b_ih (E,3)
    const float* bhh  = (const float*)d_in[7];  // b_hh (E,3)
    float* out = (float*)d_out;
    float* ws  = (float*)d_ws;
    float* gx  = ws + GX_OFF;                   // 12 MB in d_ws

    hipLaunchKernelGGL(gru_prep, dim3(48), dim3(64), 0, stream,
                       wl, bl, wih, bih, ws);
    hipLaunchKernelGGL(gru_proj, dim3(2048), dim3(256), 0, stream,
                       x, ws, gx);
    hipLaunchKernelGGL(gru_scan, dim3(128), dim3(64), 0, stream,
                       gx, st, whh, bhh, ws, out);
}

// Round 6
// 375.959 us; speedup vs baseline: 1.0533x; 1.0533x over previous
//
#include <hip/hip_runtime.h>

// Dims
#define WD 128   // W_STEPS
#define ED 16    // E
#define ND 512   // B*I
#define FD 64    // F
#define PD 72    // P = 8 + F

// Fast math: v_exp_f32 (exp2) + v_rcp_f32. ~1 ulp each.
#define LOG2E  1.44269504088896340736f
#define LOG2E2 2.88539008177792681472f
__device__ __forceinline__ float fast_sig(float x) {
    return __builtin_amdgcn_rcpf(1.0f + __builtin_amdgcn_exp2f(-LOG2E * x));
}
__device__ __forceinline__ float fast_tanh(float x) {
    // tanh = 1 - 2/(e^{2x}+1); exp2(+inf)->inf -> rcp->0 -> 1; exp2(-inf)->0 -> -1
    return 1.0f - 2.0f * __builtin_amdgcn_rcpf(1.0f + __builtin_amdgcn_exp2f(LOG2E2 * x));
}

// ---------------------------------------------------------------------------
// Prep: 48 blocks (one per (e,g) row), 64 threads (one per f).
//   Wc[eg][f] = sum_p wih[eg][p] * wl[e][p][f]          -> ws[0..3071]
//   bc[eg]    = sum_p wih[eg][p] * bl[e][p] + bih[eg]   -> ws[3072..3119]
// ---------------------------------------------------------------------------
__global__ __launch_bounds__(64) void gru_prep(
    const float* __restrict__ wl,   // (E,P,F)
    const float* __restrict__ bl,   // (E,P)
    const float* __restrict__ wih,  // (E,3,P)
    const float* __restrict__ bih,  // (E,3)
    float* __restrict__ ws)
{
    const int eg = blockIdx.x;          // 0..47
    const int e  = eg / 3;
    const int f  = threadIdx.x;         // 0..63

    const float* a = wih + eg * PD;
    const float* w = wl + (size_t)e * PD * FD + f;
    float s = 0.0f;
    #pragma unroll 8
    for (int p = 0; p < PD; ++p) s = fmaf(a[p], w[p * FD], s);
    ws[eg * FD + f] = s;

    // bc[eg]: 72-long dot via wave butterfly
    const float* b = bl + (size_t)e * PD;
    float pv = a[f] * b[f];
    if (f < 8) pv = fmaf(a[64 + f], b[64 + f], pv);
    pv += __shfl_xor(pv, 1, 64);
    pv += __shfl_xor(pv, 2, 64);
    pv += __shfl_xor(pv, 4, 64);
    pv += __shfl_xor(pv, 8, 64);
    pv += __shfl_xor(pv, 16, 64);
    pv += __shfl_xor(pv, 32, 64);
    if (f == 0) ws[ED * 3 * FD + eg] = pv + bih[eg];
}

// ---------------------------------------------------------------------------
// Main: 512 blocks x 256 threads = 2048 waves (2 waves/SIMD, 2 blocks/CU).
// Each wave owns 4 chains: lane = r*16 + c, r = chain-in-wave (0..3),
// c = f-chunk (0..15), one float4 (f = c*4..c*4+3) per lane per step.
// Butterfly xor{1,2,4,8} reduces the 64-dot within each 16-lane group;
// all lanes redundantly run the scalar GRU; lane c==0 stores h.
// Register prefetch queue depth 8, static slots (fully unrolled).
// Measured-model: BW-bound at ~45 us vs 41.3 us floor (256 MB @ 6.3 TB/s).
// ---------------------------------------------------------------------------
__global__ __launch_bounds__(256) void gru_main(
    const float* __restrict__ x,    // (W,E,N,F)
    const float* __restrict__ st,   // (E,N)
    const float* __restrict__ whh,  // (E,3)
    const float* __restrict__ bhh,  // (E,3)
    const float* __restrict__ ws,   // Wc[48][64] + bc[48]
    float* __restrict__ out)        // (W,E,N)
{
    const int lane = threadIdx.x & 63;
    const int gw   = (blockIdx.x << 2) + (threadIdx.x >> 6);  // 0..2047
    const int e    = gw >> 7;                                 // 0..15
    const int r    = lane >> 4;                               // 0..3
    const int n    = ((gw & 127) << 2) + r;                   // chain 0..511
    const int c    = lane & 15;                               // f-chunk

    const float* Wc = ws;
    const float* bc = ws + ED * 3 * FD;

    const float4 w0 = *(const float4*)(Wc + (e * 3 + 0) * FD + c * 4);
    const float4 w1 = *(const float4*)(Wc + (e * 3 + 1) * FD + c * 4);
    const float4 w2 = *(const float4*)(Wc + (e * 3 + 2) * FD + c * 4);
    const float wh0 = whh[e * 3 + 0], wh1 = whh[e * 3 + 1], wh2 = whh[e * 3 + 2];
    // fold bc into the hidden-side bias where legal (r,z gates); n-gate keeps
    // bc2 separate because bh2 is multiplied by r.
    const float B0 = bc[e * 3 + 0] + bhh[e * 3 + 0];
    const float B1 = bc[e * 3 + 1] + bhh[e * 3 + 1];
    const float bc2 = bc[e * 3 + 2];
    const float bh2 = bhh[e * 3 + 2];

    float h = st[e * ND + n];

    const float* px = x + ((size_t)e * ND + n) * FD + c * 4;
    const size_t xstr = (size_t)ED * ND * FD;   // per-w stride in floats (2 MB)
    float* po = out + (size_t)e * ND + n;
    const size_t ostr = (size_t)ED * ND;

    // prefetch queue: w = 0..7
    float4 q0, q1, q2, q3, q4, q5, q6, q7;
    q0 = *(const float4*)px; px += xstr;
    q1 = *(const float4*)px; px += xstr;
    q2 = *(const float4*)px; px += xstr;
    q3 = *(const float4*)px; px += xstr;
    q4 = *(const float4*)px; px += xstr;
    q5 = *(const float4*)px; px += xstr;
    q6 = *(const float4*)px; px += xstr;
    q7 = *(const float4*)px; px += xstr;

#define GRU_STEP(XV)                                                            \
    {                                                                           \
        float s0 = XV.x * w0.x, s1 = XV.x * w1.x, s2 = XV.x * w2.x;             \
        s0 = fmaf(XV.y, w0.y, s0); s1 = fmaf(XV.y, w1.y, s1); s2 = fmaf(XV.y, w2.y, s2); \
        s0 = fmaf(XV.z, w0.z, s0); s1 = fmaf(XV.z, w1.z, s1); s2 = fmaf(XV.z, w2.z, s2); \
        s0 = fmaf(XV.w, w0.w, s0); s1 = fmaf(XV.w, w1.w, s1); s2 = fmaf(XV.w, w2.w, s2); \
        s0 += __shfl_xor(s0, 1, 64); s1 += __shfl_xor(s1, 1, 64); s2 += __shfl_xor(s2, 1, 64); \
        s0 += __shfl_xor(s0, 2, 64); s1 += __shfl_xor(s1, 2, 64); s2 += __shfl_xor(s2, 2, 64); \
        s0 += __shfl_xor(s0, 4, 64); s1 += __shfl_xor(s1, 4, 64); s2 += __shfl_xor(s2, 4, 64); \
        s0 += __shfl_xor(s0, 8, 64); s1 += __shfl_xor(s1, 8, 64); s2 += __shfl_xor(s2, 8, 64); \
        const float rr = fast_sig(s0 + fmaf(h, wh0, B0));                       \
        const float zz = fast_sig(s1 + fmaf(h, wh1, B1));                       \
        const float nn = fast_tanh(fmaf(rr, fmaf(h, wh2, bh2), s2 + bc2));      \
        h = fmaf(zz, h - nn, nn);                                               \
        if (c == 0) *po = h;                                                    \
        po += ostr;                                                             \
    }

    for (int it = 0; it < WD / 8; ++it) {
        const bool pf = it < (WD / 8 - 1);
        { const float4 X = q0; if (pf) { q0 = *(const float4*)px; px += xstr; } GRU_STEP(X); }
        { const float4 X = q1; if (pf) { q1 = *(const float4*)px; px += xstr; } GRU_STEP(X); }
        { const float4 X = q2; if (pf) { q2 = *(const float4*)px; px += xstr; } GRU_STEP(X); }
        { const float4 X = q3; if (pf) { q3 = *(const float4*)px; px += xstr; } GRU_STEP(X); }
        { const float4 X = q4; if (pf) { q4 = *(const float4*)px; px += xstr; } GRU_STEP(X); }
        { const float4 X = q5; if (pf) { q5 = *(const float4*)px; px += xstr; } GRU_STEP(X); }
        { const float4 X = q6; if (pf) { q6 = *(const float4*)px; px += xstr; } GRU_STEP(X); }
        { const float4 X = q7; if (pf) { q7 = *(const float4*)px; px += xstr; } GRU_STEP(X); }
    }
#undef GRU_STEP
}

// ---------------------------------------------------------------------------
extern "C" void kernel_launch(void* const* d_in, const int* in_sizes, int n_in,
                              void* d_out, int out_size, void* d_ws, size_t ws_size,
                              hipStream_t stream)
{
    const float* x    = (const float*)d_in[0];  // inputs (W,E,B,I,F)
    const float* st   = (const float*)d_in[1];  // state  (1,E,N,1)
    const float* wl   = (const float*)d_in[2];  // weight_linear (E,P,F)
    const float* bl   = (const float*)d_in[3];  // bias_linear   (E,P)
    const float* wih  = (const float*)d_in[4];  // w_ih (E,3,P)
    const float* whh  = (const float*)d_in[5];  // w_hh (E,3)
    const float* bih  = (const float*)d_in[6];  // b_ih (E,3)
    const float* bhh  = (const float*)d_in[7];  // b_hh (E,3)
    float* out = (float*)d_out;
    float* ws  = (float*)d_ws;                  // needs 3120 floats

    hipLaunchKernelGGL(gru_prep, dim3(48), dim3(64), 0, stream,
                       wl, bl, wih, bih, ws);
    hipLaunchKernelGGL(gru_main, dim3(512), dim3(256), 0, stream,
                       x, st, whh, bhh, ws, out);
}